// Round 8
// baseline (966.295 us; speedup 1.0000x reference)
//
#include <hip/hip_runtime.h>
#include <math.h>

#define NB 8
#define LK 4096
#define LQ 4096
#define DD 512
#define LSEL 2744
#define LPAD 2816   // 22 * 128

typedef __attribute__((ext_vector_type(8))) short bf16x8;
typedef __attribute__((ext_vector_type(4))) float f32x4;
typedef __attribute__((ext_vector_type(16))) float f32x16;

#define AS1 __attribute__((address_space(1)))
#define AS3 __attribute__((address_space(3)))

__device__ __forceinline__ unsigned short f2bf(float x) {
  unsigned u = __float_as_uint(x);
  unsigned r = (u + 0x7fffu + ((u >> 16) & 1u)) >> 16;
  return (unsigned short)r;
}

__device__ __forceinline__ unsigned fkey(float x) {
  unsigned b = __float_as_uint(x);
  return (b & 0x80000000u) ? ~b : (b | 0x80000000u);
}

__device__ __forceinline__ unsigned cvt_pk_bf16(float lo, float hi) {
  unsigned r;
  asm("v_cvt_pk_bf16_f32 %0, %1, %2" : "=v"(r) : "v"(lo), "v"(hi));
  return r;
}

// keys f32 [B][LK][D] -> keysT f32 [B][D][LK]  (+ fused bf16 cast of keys)
__global__ void k_transpose(const float* __restrict__ keys, float* __restrict__ keysT,
                            unsigned short* __restrict__ kbf) {
  __shared__ float tile[32][33];
  int b = blockIdx.z;
  int k0 = blockIdx.x * 32, d0 = blockIdx.y * 32;
  int tx = threadIdx.x, ty = threadIdx.y;
  const float* src = keys + ((size_t)b * LK + k0) * DD + d0;
#pragma unroll
  for (int i = 0; i < 4; i++) {
    float v = src[(size_t)(ty + 8 * i) * DD + tx];
    tile[ty + 8 * i][tx] = v;
    kbf[((size_t)b * LK + k0 + ty + 8 * i) * DD + d0 + tx] = f2bf(v);
  }
  __syncthreads();
  float* dst = keysT + ((size_t)b * DD + d0) * LK + k0;
#pragma unroll
  for (int i = 0; i < 4; i++) dst[(size_t)(ty + 8 * i) * LK + tx] = tile[tx][ty + 8 * i];
}

// values f32 [B][LK][D] -> chunk-tiled bf16 VT [B][LK/8][D][8keys]  (+ fused mean partials)
__global__ void k_vt(const float* __restrict__ values, unsigned short* __restrict__ vt,
                     float* __restrict__ part) {
  __shared__ float tile[32][65];
  __shared__ float psum[4][64];
  int b = blockIdx.z, k0 = blockIdx.x * 32, d0 = blockIdx.y * 64;
  int tid = threadIdx.x;
  const float* src = values + ((size_t)b * LK + k0) * DD + d0;
#pragma unroll
  for (int j = 0; j < 8; j++) {
    int li = tid + 256 * j;
    tile[li >> 6][li & 63] = src[(size_t)(li >> 6) * DD + (li & 63)];
  }
  __syncthreads();
  int c = tid >> 6, d = tid & 63;
  union { unsigned short us[8]; uint4 v; } pk;
  float fs = 0.f;
#pragma unroll
  for (int j = 0; j < 8; j++) {
    float v = tile[c * 8 + j][d];
    pk.us[j] = f2bf(v);
    fs += v;
  }
  size_t ci = ((size_t)b * (LK / 8) + (size_t)(k0 >> 3) + c) * DD + d0 + d;
  ((uint4*)vt)[ci] = pk.v;
  psum[c][d] = fs;
  __syncthreads();
  if (tid < 64) {
    float s = psum[0][tid] + psum[1][tid] + psum[2][tid] + psum[3][tid];
    part[((size_t)b * 128 + (k0 >> 5)) * DD + d0 + tid] = s;
  }
}

// per-(b,d): mean of top-LSEL of keysT row; exact radix select, 8-bit digits (4 passes),
// two-level (16 super-bin) scan instead of serial 256-bin walk
__global__ __launch_bounds__(256) void k_kreduce(const float* __restrict__ keysT, float* __restrict__ kred) {
  __shared__ unsigned keys[4096];
  __shared__ unsigned hist[256];
  __shared__ unsigned sup[16];
  __shared__ unsigned sh_pr[2];
  __shared__ double redd[256];
  __shared__ unsigned redu[256];
  int row = blockIdx.x;
  int tid = threadIdx.x;
  const float* src = keysT + (size_t)row * LK;
  for (int i = tid; i < LK; i += 256) keys[i] = fkey(src[i]);
  unsigned prefix = 0;
  int rank = LSEL;
  for (int shift = 24; shift >= 0; shift -= 8) {
    hist[tid] = 0;
    __syncthreads();
    for (int i = tid; i < LK; i += 256) {
      unsigned u = keys[i];
      if (((u >> shift) >> 8) == prefix) atomicAdd(&hist[(u >> shift) & 255], 1);
    }
    __syncthreads();
    if (tid < 16) {
      unsigned s = 0;
#pragma unroll
      for (int j = 0; j < 16; j++) s += hist[tid * 16 + j];
      sup[tid] = s;
    }
    __syncthreads();
    if (tid == 0) {
      int r = rank;
      int sb = 15;
      for (;;) {
        int c = (int)sup[sb];
        if (c >= r) break;
        r -= c;
        if (sb == 0) break;
        sb--;
      }
      int bin = sb * 16 + 15;
      for (;;) {
        int c = (int)hist[bin];
        if (c >= r) break;
        r -= c;
        if (bin == sb * 16) break;
        bin--;
      }
      sh_pr[0] = (prefix << 8) | (unsigned)bin;
      sh_pr[1] = (unsigned)r;
    }
    __syncthreads();
    prefix = sh_pr[0];
    rank = (int)sh_pr[1];
  }
  double fsum = 0.0;
  unsigned fcnt = 0;
  for (int i = tid; i < LK; i += 256) {
    unsigned u = keys[i];
    if (u > prefix) {
      unsigned bits = (u & 0x80000000u) ? (u ^ 0x80000000u) : ~u;
      fsum += (double)__uint_as_float(bits);
      fcnt++;
    }
  }
  redd[tid] = fsum; redu[tid] = fcnt;
  __syncthreads();
  for (int s = 128; s > 0; s >>= 1) {
    if (tid < s) { redd[tid] += redd[tid + s]; redu[tid] += redu[tid + s]; }
    __syncthreads();
  }
  if (tid == 0) {
    unsigned u = prefix;
    unsigned bits = (u & 0x80000000u) ? (u ^ 0x80000000u) : ~u;
    float tval = __uint_as_float(bits);
    kred[row] = (float)((redd[0] + (double)(LSEL - (int)redu[0]) * (double)tval) / (double)LSEL);
  }
}

// sqk[b][q] = dot(K_reduce[b], queries[b][q]) with f64 accumulation
__global__ __launch_bounds__(256) void k_sqk(const float* __restrict__ queries, const float* __restrict__ kred,
                                             float* __restrict__ sqk) {
  int gw = blockIdx.x * 4 + (threadIdx.x >> 6);
  int lane = threadIdx.x & 63;
  int b = gw >> 12;
  const float* qp = queries + (size_t)gw * DD;
  const float* kp = kred + (size_t)b * DD;
  float4 a0 = ((const float4*)qp)[lane * 2];
  float4 a1 = ((const float4*)qp)[lane * 2 + 1];
  float4 c0 = ((const float4*)kp)[lane * 2];
  float4 c1 = ((const float4*)kp)[lane * 2 + 1];
  double s = (double)a0.x * c0.x + (double)a0.y * c0.y + (double)a0.z * c0.z + (double)a0.w * c0.w +
             (double)a1.x * c1.x + (double)a1.y * c1.y + (double)a1.z * c1.z + (double)a1.w * c1.w;
#pragma unroll
  for (int m = 1; m < 64; m <<= 1) s += __shfl_xor(s, m);
  if (lane == 0) sqk[gw] = (float)s;
}

// per-batch: exact top-LSEL selection (ties by lowest index) + per-row selection flags
__global__ __launch_bounds__(512) void k_select(const float* __restrict__ sqk, int* __restrict__ qidx,
                                                unsigned char* __restrict__ selflag) {
  __shared__ float vals[4096];
  __shared__ unsigned hist[16];
  __shared__ unsigned wsum[8];
  int b = blockIdx.x, tid = threadIdx.x;
  const float* src = sqk + (size_t)b * LQ;
  for (int i = tid; i < LQ; i += 512) vals[i] = src[i];
  __syncthreads();
  unsigned prefix = 0;
  int rank = LSEL;
  for (int shift = 28; shift >= 0; shift -= 4) {
    if (tid < 16) hist[tid] = 0;
    __syncthreads();
    unsigned cnt[16];
#pragma unroll
    for (int j = 0; j < 16; j++) cnt[j] = 0;
    for (int i = tid; i < LQ; i += 512) {
      unsigned u = fkey(vals[i]);
      if (((u >> shift) >> 4) == prefix) cnt[(u >> shift) & 15]++;
    }
#pragma unroll
    for (int j = 0; j < 16; j++) if (cnt[j]) atomicAdd(&hist[j], cnt[j]);
    __syncthreads();
    int r = rank;
    unsigned bin = 15;
    for (;;) {
      int c = (int)hist[bin];
      if (c >= r) break;
      r -= c;
      if (bin == 0) break;
      bin--;
    }
    prefix = (prefix << 4) | bin;
    rank = r;
    __syncthreads();
  }
  unsigned gt = 0, eq = 0;
#pragma unroll
  for (int j = 0; j < 8; j++) {
    int i = tid * 8 + j;
    unsigned u = fkey(vals[i]);
    gt += (u > prefix) ? 1u : 0u;
    eq += (u == prefix) ? 1u : 0u;
  }
  unsigned packed = (gt << 16) | eq;
  unsigned x = packed;
  int lane = tid & 63, wv = tid >> 6;
#pragma unroll
  for (int off2 = 1; off2 < 64; off2 <<= 1) {
    unsigned t = __shfl_up(x, off2);
    if (lane >= off2) x += t;
  }
  if (lane == 63) wsum[wv] = x;
  __syncthreads();
  unsigned wpre = 0, total = 0;
#pragma unroll
  for (int i = 0; i < 8; i++) {
    unsigned v = wsum[i];
    if (i < wv) wpre += v;
    total += v;
  }
  unsigned exclv = x + wpre - packed;
  unsigned total_gt = total >> 16;
  unsigned need_eq = (unsigned)LSEL - total_gt;
  unsigned gpos = exclv >> 16;
  unsigned epos = exclv & 0xffffu;
  for (int j = 0; j < 8; j++) {
    int i = tid * 8 + j;
    unsigned u = fkey(vals[i]);
    unsigned char fl = 0;
    if (u > prefix) {
      qidx[(size_t)b * LPAD + gpos] = i;
      gpos++;
      fl = 1;
    } else if (u == prefix) {
      if (epos < need_eq) {
        qidx[(size_t)b * LPAD + total_gt + epos] = i;
        fl = 1;
      }
      epos++;
    }
    selflag[(size_t)b * LQ + i] = fl;
  }
  for (int p = LSEL + tid; p < LPAD; p += 512) qidx[(size_t)b * LPAD + p] = -1;
}

// gather selected queries -> bf16 [B][LPAD][D], PRE-SCALED by 1/sqrt(D)*log2(e); pad rows zero
__global__ void k_gather(const float* __restrict__ queries, const int* __restrict__ qidx,
                         unsigned short* __restrict__ qs) {
  const float QSCL = 0.04419417418f * 1.4426950408889634f;
  int r = blockIdx.x, b = blockIdx.y;
  int tid = threadIdx.x;
  int q = qidx[(size_t)b * LPAD + r];
  ushort4* dst = (ushort4*)(qs + ((size_t)b * LPAD + r) * DD);
  if (q < 0) {
    ushort4 z; z.x = 0; z.y = 0; z.z = 0; z.w = 0;
    dst[tid] = z;
  } else {
    const float4* srcv = (const float4*)(queries + ((size_t)b * LQ + q) * DD);
    float4 v = srcv[tid];
    ushort4 o;
    o.x = f2bf(v.x * QSCL); o.y = f2bf(v.y * QSCL);
    o.z = f2bf(v.z * QSCL); o.w = f2bf(v.w * QSCL);
    dst[tid] = o;
  }
}

__global__ void k_meanv_fin(const float* __restrict__ part, float* __restrict__ meanv) {
  int d = blockIdx.x * 256 + threadIdx.x;
  int b = blockIdx.y;
  float s = 0.f;
  for (int i = 0; i < 128; i++) s += part[((size_t)b * 128 + i) * DD + d];
  meanv[(size_t)b * DD + d] = s * (1.0f / 4096.0f);
}

// fill ONLY unselected rows with mean-of-values
__global__ void k_fill(float4* __restrict__ out4, const float4* __restrict__ mv4,
                       const unsigned char* __restrict__ flag) {
  int row = blockIdx.x * 2 + (threadIdx.x >> 7);
  int t = threadIdx.x & 127;
  if (flag[row]) return;
  int b = row >> 12;
  out4[(size_t)row * 128 + t] = mv4[b * 128 + t];
}

// flash attention v8: 8 waves = 4 q-groups x 2 d-waves, Q-tile 128, 32x32x16
// swapped-operand MFMA. K fed DIRECTLY L2->registers (A-frag layout == kbf row layout,
// immediate-offset loads, 2x4-frag rotation) -- no K LDS staging, no K ds_reads.
// V LDS-dbuf via global_load_lds. batch->XCD swizzle, in-lane softmax, in-register P.
__global__ __launch_bounds__(512, 2) void k_attn(const unsigned short* __restrict__ qs,
                                                 const unsigned short* __restrict__ kbf,
                                                 const unsigned short* __restrict__ vt,
                                                 const int* __restrict__ qidx,
                                                 float* __restrict__ out) {
  extern __shared__ char smem[];  // V dbuf [2][32KB] @0 | Sx [8][4KB] @65536
  int bi = blockIdx.x;
  int b = bi & 7;              // batch == XCD (round-robin dispatch)
  int q0 = (bi >> 3) * 128;    // 22 q-chunks per batch
  int tid = threadIdx.x;
  int w = tid >> 6, lane = tid & 63;
  int l31 = lane & 31, h = lane >> 5;
  int qg = w >> 1, dg = w & 1;

  // Q as B-frags over this wave's d-slice: lane holds Q[q=l31][dg*256 + t*16 + h*8 ..+7]
  const unsigned short* qrow = qs + ((size_t)b * LPAD + q0 + qg * 32 + l31) * DD + dg * 256;
  bf16x8 qb[16];
#pragma unroll
  for (int t = 0; t < 16; t++) qb[t] = *(const bf16x8*)(qrow + t * 16 + h * 8);

  f32x16 O[8];
#pragma unroll
  for (int n = 0; n < 8; n++)
#pragma unroll
    for (int j = 0; j < 16; j++) O[n][j] = 0.f;
  float m_run = -1e30f, l_run = 0.f;  // per-lane (q = l31, k-half = h)

  const char* gK = (const char*)(kbf + (size_t)b * LK * DD);
  const char* gV = (const char*)vt;

  // V LDS: linear copy of VT tile [4 c][512 d][8k]; wave w stages slabs {w, w+8, w+16, w+24}
#define STAGE(KT, BUF)                                                                          \
  do {                                                                                          \
    char* Vd = smem + (size_t)(BUF)*32768;                                                      \
    const char* vsrc = gV + ((size_t)b * 512 + (size_t)(KT)*4) * 8192 + lane * 16;              \
    _Pragma("unroll") for (int j = 0; j < 4; j++) {                                             \
      int s = w + 8 * j;                                                                        \
      __builtin_amdgcn_global_load_lds((const AS1 unsigned int*)(uintptr_t)(vsrc + s * 1024),   \
                                       (AS3 unsigned int*)(uintptr_t)(Vd + s * 1024 +           \
                                                                      lane * 16),               \
                                       16, 0, 0);                                               \
    }                                                                                           \
  } while (0)

  STAGE(0, 0);
  __syncthreads();
  int cur = 0;

  char* mySx = smem + 65536 + (size_t)w * 4096;
  const char* pSx = smem + 65536 + (size_t)(w ^ 1) * 4096;

  for (int kt = 0; kt < LK / 32; kt++) {
    if (kt + 1 < LK / 32) STAGE(kt + 1, cur ^ 1);

    const char* Vl = smem + (size_t)cur * 32768;

    // K A-frags direct from global (L2-warm): lane reads K[row=l31][dg*512B + t*32B + h*16B]
    const char* kp = gK + (size_t)kt * 32768 + (size_t)l31 * 1024 + dg * 512 + h * 16;
    bf16x8 kf0[4], kf1[4];
#pragma unroll
    for (int j = 0; j < 4; j++) kf0[j] = *(const bf16x8*)(kp + j * 32);
#pragma unroll
    for (int j = 0; j < 4; j++) kf1[j] = *(const bf16x8*)(kp + (4 + j) * 32);

    // QK^T partial (this wave's 256-d slice): S^T[32k x 32q], lane: q=l31, k=(r&3)+8*(r>>2)+4h
    f32x16 acc;
#pragma unroll
    for (int j = 0; j < 16; j++) acc[j] = 0.f;
    __builtin_amdgcn_s_setprio(1);
#pragma unroll
    for (int j = 0; j < 4; j++) acc = __builtin_amdgcn_mfma_f32_32x32x16_bf16(kf0[j], qb[j], acc, 0, 0, 0);
#pragma unroll
    for (int j = 0; j < 4; j++) kf0[j] = *(const bf16x8*)(kp + (8 + j) * 32);
#pragma unroll
    for (int j = 0; j < 4; j++) acc = __builtin_amdgcn_mfma_f32_32x32x16_bf16(kf1[j], qb[4 + j], acc, 0, 0, 0);
#pragma unroll
    for (int j = 0; j < 4; j++) kf1[j] = *(const bf16x8*)(kp + (12 + j) * 32);
#pragma unroll
    for (int j = 0; j < 4; j++) acc = __builtin_amdgcn_mfma_f32_32x32x16_bf16(kf0[j], qb[8 + j], acc, 0, 0, 0);
#pragma unroll
    for (int j = 0; j < 4; j++) acc = __builtin_amdgcn_mfma_f32_32x32x16_bf16(kf1[j], qb[12 + j], acc, 0, 0, 0);
    __builtin_amdgcn_s_setprio(0);

    // exchange partial S with d-partner wave (linear b128, conflict-free)
#pragma unroll
    for (int j = 0; j < 4; j++) {
      f32x4 v4 = {acc[4 * j], acc[4 * j + 1], acc[4 * j + 2], acc[4 * j + 3]};
      *(f32x4*)(mySx + j * 1024 + lane * 16) = v4;
    }
    asm volatile("s_waitcnt lgkmcnt(0)\ns_barrier" ::: "memory");
#pragma unroll
    for (int j = 0; j < 4; j++) {
      f32x4 v4 = *(const f32x4*)(pSx + j * 1024 + lane * 16);
      acc[4 * j] += v4[0];
      acc[4 * j + 1] += v4[1];
      acc[4 * j + 2] += v4[2];
      acc[4 * j + 3] += v4[3];
    }

    // in-lane softmax (log2 domain; Q pre-scaled by SCALE*log2e)
    float mx = acc[0];
#pragma unroll
    for (int r = 1; r < 16; r++) mx = fmaxf(mx, acc[r]);
    mx = fmaxf(mx, __shfl_xor(mx, 32));
    if (!__all(mx - m_run <= 11.5f)) {
      float mn = fmaxf(m_run, mx);
      float f = exp2f(m_run - mn);
      m_run = mn;
      l_run *= f;
#pragma unroll
      for (int r = 0; r < 16; r++) {
        float fr = __shfl(f, (r & 3) + 8 * (r >> 2) + 4 * h);
#pragma unroll
        for (int n = 0; n < 8; n++) O[n][r] *= fr;
      }
    }
    float ps = 0.f;
#pragma unroll
    for (int r = 0; r < 16; r++) {
      acc[r] = exp2f(acc[r] - m_run);
      ps += acc[r];
    }
    l_run += ps;

    // pack P to bf16 pairs; exchange halves; assemble PV A-frags (layout verified R4)
    unsigned pw[8], px[8];
#pragma unroll
    for (int i = 0; i < 8; i++) pw[i] = cvt_pk_bf16(acc[2 * i], acc[2 * i + 1]);
#pragma unroll
    for (int i = 0; i < 8; i++) px[i] = __shfl_xor(pw[i], 32);
    union { unsigned u[4]; bf16x8 v; } A0, A1;
    A0.u[0] = h ? px[2] : pw[0];
    A0.u[1] = h ? px[3] : pw[1];
    A0.u[2] = h ? pw[2] : px[0];
    A0.u[3] = h ? pw[3] : px[1];
    A1.u[0] = h ? px[6] : pw[4];
    A1.u[1] = h ? px[7] : pw[5];
    A1.u[2] = h ? pw[6] : px[4];
    A1.u[3] = h ? pw[7] : px[5];

    // PV on this wave's 256-d slice: O[32q x 256d] += P[32q x 32k] * V[32k x 256d]
    const char* Vp = Vl + (size_t)h * 8192 + dg * 4096 + l31 * 16;
    __builtin_amdgcn_s_setprio(1);
#pragma unroll
    for (int n = 0; n < 8; n++) {
      bf16x8 b0 = *(const bf16x8*)(Vp + n * 512);
      O[n] = __builtin_amdgcn_mfma_f32_32x32x16_bf16(A0.v, b0, O[n], 0, 0, 0);
      bf16x8 b1 = *(const bf16x8*)(Vp + 16384 + n * 512);
      O[n] = __builtin_amdgcn_mfma_f32_32x32x16_bf16(A1.v, b1, O[n], 0, 0, 0);
    }
    __builtin_amdgcn_s_setprio(0);

    __syncthreads();  // staged V kt+1 drained (vmcnt 0) + all waves done with cur buf + Sx
    cur ^= 1;
  }

  // epilogue: combine k-halves of l, scale, scatter
  float lt = l_run + __shfl_xor(l_run, 32);
  float linv = 1.0f / lt;
  const int* qx = qidx + (size_t)b * LPAD + q0 + qg * 32;
#pragma unroll
  for (int r = 0; r < 16; r++) {
    int row = (r & 3) + 8 * (r >> 2) + 4 * h;
    float sc = __shfl(linv, row);
    int qq = qx[row];
    if (qq >= 0) {
      float* orow = out + ((size_t)b * LQ + qq) * DD + dg * 256 + l31;
#pragma unroll
      for (int n = 0; n < 8; n++) orow[n * 32] = O[n][r] * sc;
    }
  }
#undef STAGE
}

extern "C" void kernel_launch(void* const* d_in, const int* in_sizes, int n_in,
                              void* d_out, int out_size, void* d_ws, size_t ws_size,
                              hipStream_t stream) {
  const float* queries = (const float*)d_in[0];
  const float* keys = (const float*)d_in[1];
  const float* values = (const float*)d_in[2];
  float* out = (float*)d_out;
  char* ws = (char*)d_ws;
  size_t off = 0;
  float* keysT = (float*)(ws + off); off += (size_t)NB * DD * LK * 4;                 // 64 MB
  unsigned short* kbf = (unsigned short*)(ws + off); off += (size_t)NB * LK * DD * 2; // 32 MB
  unsigned short* vt = (unsigned short*)(ws + off); off += (size_t)NB * LK * DD * 2;  // 32 MB
  float* kred = (float*)(ws + off); off += (size_t)NB * DD * 4;
  float* sqkv = (float*)(ws + off); off += (size_t)NB * LQ * 4;
  int* qidx = (int*)(ws + off); off += (size_t)NB * LPAD * 4;
  float* part = (float*)(ws + off); off += (size_t)NB * 128 * DD * 4;                 // 2 MB
  float* meanv = (float*)(ws + off); off += (size_t)NB * DD * 4;
  unsigned char* selflag = (unsigned char*)(ws + off); off += (size_t)NB * LQ;
  // qs aliases keysT's region: keysT dead after k_kreduce, qs written by k_gather after it
  unsigned short* qs = (unsigned short*)keysT;  // 23.1 MB < 64 MB

  hipFuncSetAttribute((const void*)k_attn, hipFuncAttributeMaxDynamicSharedMemorySize, 98304);

  k_transpose<<<dim3(LK / 32, DD / 32, NB), dim3(32, 8), 0, stream>>>(keys, keysT, kbf);
  k_vt<<<dim3(LK / 32, DD / 64, NB), 256, 0, stream>>>(values, vt, part);
  k_kreduce<<<NB * DD, 256, 0, stream>>>(keysT, kred);
  k_sqk<<<NB * LQ / 4, 256, 0, stream>>>(queries, kred, sqkv);
  k_select<<<NB, 512, 0, stream>>>(sqkv, qidx, selflag);
  k_gather<<<dim3(LPAD, NB), 128, 0, stream>>>(queries, qidx, qs);
  k_meanv_fin<<<dim3(DD / 256, NB), 256, 0, stream>>>(part, meanv);
  k_fill<<<NB * LQ / 2, 256, 0, stream>>>((float4*)out, (const float4*)meanv, selflag);
  k_attn<<<dim3((LPAD / 128) * NB), 512, 98304, stream>>>(qs, kbf, vt, qidx, out);
}

// Round 9
// 843.572 us; speedup vs baseline: 1.1455x; 1.1455x over previous
//
#include <hip/hip_runtime.h>
#include <math.h>

#define NB 8
#define LK 4096
#define LQ 4096
#define DD 512
#define LSEL 2744
#define LPAD 2816   // 44 * 64

typedef __attribute__((ext_vector_type(8))) short bf16x8;
typedef __attribute__((ext_vector_type(4))) float f32x4;
typedef __attribute__((ext_vector_type(16))) float f32x16;

#define AS1 __attribute__((address_space(1)))
#define AS3 __attribute__((address_space(3)))

__device__ __forceinline__ unsigned short f2bf(float x) {
  unsigned u = __float_as_uint(x);
  unsigned r = (u + 0x7fffu + ((u >> 16) & 1u)) >> 16;
  return (unsigned short)r;
}

__device__ __forceinline__ unsigned fkey(float x) {
  unsigned b = __float_as_uint(x);
  return (b & 0x80000000u) ? ~b : (b | 0x80000000u);
}

__device__ __forceinline__ unsigned cvt_pk_bf16(float lo, float hi) {
  unsigned r;
  asm("v_cvt_pk_bf16_f32 %0, %1, %2" : "=v"(r) : "v"(lo), "v"(hi));
  return r;
}

// keys f32 [B][LK][D] -> keysT f32 [B][D][LK]  (+ fused bf16 cast of keys)
__global__ void k_transpose(const float* __restrict__ keys, float* __restrict__ keysT,
                            unsigned short* __restrict__ kbf) {
  __shared__ float tile[32][33];
  int b = blockIdx.z;
  int k0 = blockIdx.x * 32, d0 = blockIdx.y * 32;
  int tx = threadIdx.x, ty = threadIdx.y;
  const float* src = keys + ((size_t)b * LK + k0) * DD + d0;
#pragma unroll
  for (int i = 0; i < 4; i++) {
    float v = src[(size_t)(ty + 8 * i) * DD + tx];
    tile[ty + 8 * i][tx] = v;
    kbf[((size_t)b * LK + k0 + ty + 8 * i) * DD + d0 + tx] = f2bf(v);
  }
  __syncthreads();
  float* dst = keysT + ((size_t)b * DD + d0) * LK + k0;
#pragma unroll
  for (int i = 0; i < 4; i++) dst[(size_t)(ty + 8 * i) * LK + tx] = tile[tx][ty + 8 * i];
}

// values f32 [B][LK][D] -> chunk-tiled bf16 VT [B][LK/8][D][8keys]  (+ fused mean partials)
__global__ void k_vt(const float* __restrict__ values, unsigned short* __restrict__ vt,
                     float* __restrict__ part) {
  __shared__ float tile[32][65];
  __shared__ float psum[4][64];
  int b = blockIdx.z, k0 = blockIdx.x * 32, d0 = blockIdx.y * 64;
  int tid = threadIdx.x;
  const float* src = values + ((size_t)b * LK + k0) * DD + d0;
#pragma unroll
  for (int j = 0; j < 8; j++) {
    int li = tid + 256 * j;
    tile[li >> 6][li & 63] = src[(size_t)(li >> 6) * DD + (li & 63)];
  }
  __syncthreads();
  int c = tid >> 6, d = tid & 63;
  union { unsigned short us[8]; uint4 v; } pk;
  float fs = 0.f;
#pragma unroll
  for (int j = 0; j < 8; j++) {
    float v = tile[c * 8 + j][d];
    pk.us[j] = f2bf(v);
    fs += v;
  }
  size_t ci = ((size_t)b * (LK / 8) + (size_t)(k0 >> 3) + c) * DD + d0 + d;
  ((uint4*)vt)[ci] = pk.v;
  psum[c][d] = fs;
  __syncthreads();
  if (tid < 64) {
    float s = psum[0][tid] + psum[1][tid] + psum[2][tid] + psum[3][tid];
    part[((size_t)b * 128 + (k0 >> 5)) * DD + d0 + tid] = s;
  }
}

// per-(b,d): mean of top-LSEL of keysT row; exact radix select, 8-bit digits (4 passes),
// two-level (16 super-bin) scan
__global__ __launch_bounds__(256) void k_kreduce(const float* __restrict__ keysT, float* __restrict__ kred) {
  __shared__ unsigned keys[4096];
  __shared__ unsigned hist[256];
  __shared__ unsigned sup[16];
  __shared__ unsigned sh_pr[2];
  __shared__ double redd[256];
  __shared__ unsigned redu[256];
  int row = blockIdx.x;
  int tid = threadIdx.x;
  const float* src = keysT + (size_t)row * LK;
  for (int i = tid; i < LK; i += 256) keys[i] = fkey(src[i]);
  unsigned prefix = 0;
  int rank = LSEL;
  for (int shift = 24; shift >= 0; shift -= 8) {
    hist[tid] = 0;
    __syncthreads();
    for (int i = tid; i < LK; i += 256) {
      unsigned u = keys[i];
      if (((u >> shift) >> 8) == prefix) atomicAdd(&hist[(u >> shift) & 255], 1);
    }
    __syncthreads();
    if (tid < 16) {
      unsigned s = 0;
#pragma unroll
      for (int j = 0; j < 16; j++) s += hist[tid * 16 + j];
      sup[tid] = s;
    }
    __syncthreads();
    if (tid == 0) {
      int r = rank;
      int sb = 15;
      for (;;) {
        int c = (int)sup[sb];
        if (c >= r) break;
        r -= c;
        if (sb == 0) break;
        sb--;
      }
      int bin = sb * 16 + 15;
      for (;;) {
        int c = (int)hist[bin];
        if (c >= r) break;
        r -= c;
        if (bin == sb * 16) break;
        bin--;
      }
      sh_pr[0] = (prefix << 8) | (unsigned)bin;
      sh_pr[1] = (unsigned)r;
    }
    __syncthreads();
    prefix = sh_pr[0];
    rank = (int)sh_pr[1];
  }
  double fsum = 0.0;
  unsigned fcnt = 0;
  for (int i = tid; i < LK; i += 256) {
    unsigned u = keys[i];
    if (u > prefix) {
      unsigned bits = (u & 0x80000000u) ? (u ^ 0x80000000u) : ~u;
      fsum += (double)__uint_as_float(bits);
      fcnt++;
    }
  }
  redd[tid] = fsum; redu[tid] = fcnt;
  __syncthreads();
  for (int s = 128; s > 0; s >>= 1) {
    if (tid < s) { redd[tid] += redd[tid + s]; redu[tid] += redu[tid + s]; }
    __syncthreads();
  }
  if (tid == 0) {
    unsigned u = prefix;
    unsigned bits = (u & 0x80000000u) ? (u ^ 0x80000000u) : ~u;
    float tval = __uint_as_float(bits);
    kred[row] = (float)((redd[0] + (double)(LSEL - (int)redu[0]) * (double)tval) / (double)LSEL);
  }
}

// sqk[b][q] = dot(K_reduce[b], queries[b][q]) with f64 accumulation
__global__ __launch_bounds__(256) void k_sqk(const float* __restrict__ queries, const float* __restrict__ kred,
                                             float* __restrict__ sqk) {
  int gw = blockIdx.x * 4 + (threadIdx.x >> 6);
  int lane = threadIdx.x & 63;
  int b = gw >> 12;
  const float* qp = queries + (size_t)gw * DD;
  const float* kp = kred + (size_t)b * DD;
  float4 a0 = ((const float4*)qp)[lane * 2];
  float4 a1 = ((const float4*)qp)[lane * 2 + 1];
  float4 c0 = ((const float4*)kp)[lane * 2];
  float4 c1 = ((const float4*)kp)[lane * 2 + 1];
  double s = (double)a0.x * c0.x + (double)a0.y * c0.y + (double)a0.z * c0.z + (double)a0.w * c0.w +
             (double)a1.x * c1.x + (double)a1.y * c1.y + (double)a1.z * c1.z + (double)a1.w * c1.w;
#pragma unroll
  for (int m = 1; m < 64; m <<= 1) s += __shfl_xor(s, m);
  if (lane == 0) sqk[gw] = (float)s;
}

// per-batch: exact top-LSEL selection (ties by lowest index) + per-row selection flags
__global__ __launch_bounds__(512) void k_select(const float* __restrict__ sqk, int* __restrict__ qidx,
                                                unsigned char* __restrict__ selflag) {
  __shared__ float vals[4096];
  __shared__ unsigned hist[16];
  __shared__ unsigned wsum[8];
  int b = blockIdx.x, tid = threadIdx.x;
  const float* src = sqk + (size_t)b * LQ;
  for (int i = tid; i < LQ; i += 512) vals[i] = src[i];
  __syncthreads();
  unsigned prefix = 0;
  int rank = LSEL;
  for (int shift = 28; shift >= 0; shift -= 4) {
    if (tid < 16) hist[tid] = 0;
    __syncthreads();
    unsigned cnt[16];
#pragma unroll
    for (int j = 0; j < 16; j++) cnt[j] = 0;
    for (int i = tid; i < LQ; i += 512) {
      unsigned u = fkey(vals[i]);
      if (((u >> shift) >> 4) == prefix) cnt[(u >> shift) & 15]++;
    }
#pragma unroll
    for (int j = 0; j < 16; j++) if (cnt[j]) atomicAdd(&hist[j], cnt[j]);
    __syncthreads();
    int r = rank;
    unsigned bin = 15;
    for (;;) {
      int c = (int)hist[bin];
      if (c >= r) break;
      r -= c;
      if (bin == 0) break;
      bin--;
    }
    prefix = (prefix << 4) | bin;
    rank = r;
    __syncthreads();
  }
  unsigned gt = 0, eq = 0;
#pragma unroll
  for (int j = 0; j < 8; j++) {
    int i = tid * 8 + j;
    unsigned u = fkey(vals[i]);
    gt += (u > prefix) ? 1u : 0u;
    eq += (u == prefix) ? 1u : 0u;
  }
  unsigned packed = (gt << 16) | eq;
  unsigned x = packed;
  int lane = tid & 63, wv = tid >> 6;
#pragma unroll
  for (int off2 = 1; off2 < 64; off2 <<= 1) {
    unsigned t = __shfl_up(x, off2);
    if (lane >= off2) x += t;
  }
  if (lane == 63) wsum[wv] = x;
  __syncthreads();
  unsigned wpre = 0, total = 0;
#pragma unroll
  for (int i = 0; i < 8; i++) {
    unsigned v = wsum[i];
    if (i < wv) wpre += v;
    total += v;
  }
  unsigned exclv = x + wpre - packed;
  unsigned total_gt = total >> 16;
  unsigned need_eq = (unsigned)LSEL - total_gt;
  unsigned gpos = exclv >> 16;
  unsigned epos = exclv & 0xffffu;
  for (int j = 0; j < 8; j++) {
    int i = tid * 8 + j;
    unsigned u = fkey(vals[i]);
    unsigned char fl = 0;
    if (u > prefix) {
      qidx[(size_t)b * LPAD + gpos] = i;
      gpos++;
      fl = 1;
    } else if (u == prefix) {
      if (epos < need_eq) {
        qidx[(size_t)b * LPAD + total_gt + epos] = i;
        fl = 1;
      }
      epos++;
    }
    selflag[(size_t)b * LQ + i] = fl;
  }
  for (int p = LSEL + tid; p < LPAD; p += 512) qidx[(size_t)b * LPAD + p] = -1;
}

// gather selected queries -> bf16 [B][LPAD][D], PRE-SCALED by 1/sqrt(D)*log2(e); pad rows zero
__global__ void k_gather(const float* __restrict__ queries, const int* __restrict__ qidx,
                         unsigned short* __restrict__ qs) {
  const float QSCL = 0.04419417418f * 1.4426950408889634f;
  int r = blockIdx.x, b = blockIdx.y;
  int tid = threadIdx.x;
  int q = qidx[(size_t)b * LPAD + r];
  ushort4* dst = (ushort4*)(qs + ((size_t)b * LPAD + r) * DD);
  if (q < 0) {
    ushort4 z; z.x = 0; z.y = 0; z.z = 0; z.w = 0;
    dst[tid] = z;
  } else {
    const float4* srcv = (const float4*)(queries + ((size_t)b * LQ + q) * DD);
    float4 v = srcv[tid];
    ushort4 o;
    o.x = f2bf(v.x * QSCL); o.y = f2bf(v.y * QSCL);
    o.z = f2bf(v.z * QSCL); o.w = f2bf(v.w * QSCL);
    dst[tid] = o;
  }
}

__global__ void k_meanv_fin(const float* __restrict__ part, float* __restrict__ meanv) {
  int d = blockIdx.x * 256 + threadIdx.x;
  int b = blockIdx.y;
  float s = 0.f;
  for (int i = 0; i < 128; i++) s += part[((size_t)b * 128 + i) * DD + d];
  meanv[(size_t)b * DD + d] = s * (1.0f / 4096.0f);
}

// fill ONLY unselected rows with mean-of-values
__global__ void k_fill(float4* __restrict__ out4, const float4* __restrict__ mv4,
                       const unsigned char* __restrict__ flag) {
  int row = blockIdx.x * 2 + (threadIdx.x >> 7);
  int t = threadIdx.x & 127;
  if (flag[row]) return;
  int b = row >> 12;
  out4[(size_t)row * 128 + t] = mv4[b * 128 + t];
}

// flash attention v9: R7 per-wave structure, finer grid. 4 waves = 2 qg x 2 dg, Q-tile 64,
// 352 blocks (44/batch -> all 256 CUs busy in round 1). K+V LDS dbuf via global_load_lds,
// batch->XCD swizzle, Sx partial-S exchange, in-lane softmax, in-register P, setprio.
__global__ __launch_bounds__(256, 1) void k_attn(const unsigned short* __restrict__ qs,
                                                 const unsigned short* __restrict__ kbf,
                                                 const unsigned short* __restrict__ vt,
                                                 const int* __restrict__ qidx,
                                                 float* __restrict__ out) {
  extern __shared__ char smem[];  // K dbuf [2][32KB] @0 | V dbuf [2][32KB] @65536 | Sx [4][4KB] @131072
  int bi = blockIdx.x;
  int b = bi & 7;              // batch == XCD (round-robin dispatch)
  int q0 = (bi >> 3) * 64;     // 44 q-chunks per batch
  int tid = threadIdx.x;
  int w = tid >> 6, lane = tid & 63;
  int l31 = lane & 31, h = lane >> 5;
  int qg = w >> 1, dg = w & 1;

  // Q as B-frags over this wave's d-slice: lane holds Q[q=l31][dg*256 + t*16 + h*8 ..+7]
  const unsigned short* qrow = qs + ((size_t)b * LPAD + q0 + qg * 32 + l31) * DD + dg * 256;
  bf16x8 qb[16];
#pragma unroll
  for (int t = 0; t < 16; t++) qb[t] = *(const bf16x8*)(qrow + t * 16 + h * 8);

  f32x16 O[8];
#pragma unroll
  for (int n = 0; n < 8; n++)
#pragma unroll
    for (int j = 0; j < 16; j++) O[n][j] = 0.f;
  float m_run = -1e30f, l_run = 0.f;  // per-lane (q = l31, k-half = h)

  const char* gK = (const char*)(kbf + (size_t)b * LK * DD);
  const char* gV = (const char*)vt;

  // K LDS: chunk-major [32 c][2 h][32 rows][16B] x2buf; V LDS: linear VT tile [4 c][512 d][8k]
  // wave w stages K chunks {w+4j} and V slabs {w+4j}, j=0..7
#define STAGE(KT, BUF)                                                                          \
  do {                                                                                          \
    char* Kd = smem + (size_t)(BUF)*32768;                                                      \
    char* Vd = smem + 65536 + (size_t)(BUF)*32768;                                              \
    const char* ksrc = gK + (size_t)(KT)*32768 + (size_t)l31 * 1024 + h * 16;                   \
    const char* vsrc = gV + ((size_t)b * 512 + (size_t)(KT)*4) * 8192 + lane * 16;              \
    _Pragma("unroll") for (int j = 0; j < 8; j++) {                                             \
      int u = w + 4 * j;                                                                        \
      __builtin_amdgcn_global_load_lds((const AS1 unsigned int*)(uintptr_t)(ksrc + u * 32),     \
                                       (AS3 unsigned int*)(uintptr_t)(Kd + u * 1024 +           \
                                                                      lane * 16),               \
                                       16, 0, 0);                                               \
    }                                                                                           \
    _Pragma("unroll") for (int j = 0; j < 8; j++) {                                             \
      int s = w + 4 * j;                                                                        \
      __builtin_amdgcn_global_load_lds((const AS1 unsigned int*)(uintptr_t)(vsrc + s * 1024),   \
                                       (AS3 unsigned int*)(uintptr_t)(Vd + s * 1024 +           \
                                                                      lane * 16),               \
                                       16, 0, 0);                                               \
    }                                                                                           \
  } while (0)

  STAGE(0, 0);
  __syncthreads();
  int cur = 0;

  char* mySx = smem + 131072 + (size_t)w * 4096;
  const char* pSx = smem + 131072 + (size_t)(w ^ 1) * 4096;

  for (int kt = 0; kt < LK / 32; kt++) {
    if (kt + 1 < LK / 32) STAGE(kt + 1, cur ^ 1);

    const char* Kl = smem + (size_t)cur * 32768;
    const char* Vl = smem + 65536 + (size_t)cur * 32768;

    // QK^T partial (this wave's 256-d slice): S^T[32k x 32q], lane: q=l31, k=(r&3)+8*(r>>2)+4h
    f32x16 acc;
#pragma unroll
    for (int j = 0; j < 16; j++) acc[j] = 0.f;
    const char* Kp = Kl + (size_t)(dg * 32 + h) * 512 + l31 * 16;
    __builtin_amdgcn_s_setprio(1);
#pragma unroll
    for (int t = 0; t < 16; t++) {
      bf16x8 kf = *(const bf16x8*)(Kp + t * 1024);
      acc = __builtin_amdgcn_mfma_f32_32x32x16_bf16(kf, qb[t], acc, 0, 0, 0);
    }
    __builtin_amdgcn_s_setprio(0);

    // exchange partial S with d-partner wave (linear b128, conflict-free)
#pragma unroll
    for (int j = 0; j < 4; j++) {
      f32x4 v4 = {acc[4 * j], acc[4 * j + 1], acc[4 * j + 2], acc[4 * j + 3]};
      *(f32x4*)(mySx + j * 1024 + lane * 16) = v4;
    }
    asm volatile("s_waitcnt lgkmcnt(0)\ns_barrier" ::: "memory");
#pragma unroll
    for (int j = 0; j < 4; j++) {
      f32x4 v4 = *(const f32x4*)(pSx + j * 1024 + lane * 16);
      acc[4 * j] += v4[0];
      acc[4 * j + 1] += v4[1];
      acc[4 * j + 2] += v4[2];
      acc[4 * j + 3] += v4[3];
    }

    // in-lane softmax (log2 domain; Q pre-scaled by SCALE*log2e)
    float mx = acc[0];
#pragma unroll
    for (int r = 1; r < 16; r++) mx = fmaxf(mx, acc[r]);
    mx = fmaxf(mx, __shfl_xor(mx, 32));
    if (!__all(mx - m_run <= 11.5f)) {
      float mn = fmaxf(m_run, mx);
      float f = exp2f(m_run - mn);
      m_run = mn;
      l_run *= f;
#pragma unroll
      for (int r = 0; r < 16; r++) {
        float fr = __shfl(f, (r & 3) + 8 * (r >> 2) + 4 * h);
#pragma unroll
        for (int n = 0; n < 8; n++) O[n][r] *= fr;
      }
    }
    float ps = 0.f;
#pragma unroll
    for (int r = 0; r < 16; r++) {
      acc[r] = exp2f(acc[r] - m_run);
      ps += acc[r];
    }
    l_run += ps;

    // pack P to bf16 pairs; exchange halves; assemble PV A-frags (layout verified R4)
    unsigned pw[8], px[8];
#pragma unroll
    for (int i = 0; i < 8; i++) pw[i] = cvt_pk_bf16(acc[2 * i], acc[2 * i + 1]);
#pragma unroll
    for (int i = 0; i < 8; i++) px[i] = __shfl_xor(pw[i], 32);
    union { unsigned u[4]; bf16x8 v; } A0, A1;
    A0.u[0] = h ? px[2] : pw[0];
    A0.u[1] = h ? px[3] : pw[1];
    A0.u[2] = h ? pw[2] : px[0];
    A0.u[3] = h ? pw[3] : px[1];
    A1.u[0] = h ? px[6] : pw[4];
    A1.u[1] = h ? px[7] : pw[5];
    A1.u[2] = h ? pw[6] : px[4];
    A1.u[3] = h ? pw[7] : px[5];

    // PV on this wave's 256-d slice: O[32q x 256d] += P[32q x 32k] * V[32k x 256d]
    const char* Vp = Vl + (size_t)h * 8192 + dg * 4096 + l31 * 16;
    __builtin_amdgcn_s_setprio(1);
#pragma unroll
    for (int n = 0; n < 8; n++) {
      bf16x8 b0 = *(const bf16x8*)(Vp + n * 512);
      O[n] = __builtin_amdgcn_mfma_f32_32x32x16_bf16(A0.v, b0, O[n], 0, 0, 0);
      bf16x8 b1 = *(const bf16x8*)(Vp + 16384 + n * 512);
      O[n] = __builtin_amdgcn_mfma_f32_32x32x16_bf16(A1.v, b1, O[n], 0, 0, 0);
    }
    __builtin_amdgcn_s_setprio(0);

    __syncthreads();  // staged kt+1 drained (vmcnt 0) + all waves done with cur bufs + Sx
    cur ^= 1;
  }

  // epilogue: combine k-halves of l, scale, scatter
  float lt = l_run + __shfl_xor(l_run, 32);
  float linv = 1.0f / lt;
  const int* qx = qidx + (size_t)b * LPAD + q0 + qg * 32;
#pragma unroll
  for (int r = 0; r < 16; r++) {
    int row = (r & 3) + 8 * (r >> 2) + 4 * h;
    float sc = __shfl(linv, row);
    int qq = qx[row];
    if (qq >= 0) {
      float* orow = out + ((size_t)b * LQ + qq) * DD + dg * 256 + l31;
#pragma unroll
      for (int n = 0; n < 8; n++) orow[n * 32] = O[n][r] * sc;
    }
  }
#undef STAGE
}

extern "C" void kernel_launch(void* const* d_in, const int* in_sizes, int n_in,
                              void* d_out, int out_size, void* d_ws, size_t ws_size,
                              hipStream_t stream) {
  const float* queries = (const float*)d_in[0];
  const float* keys = (const float*)d_in[1];
  const float* values = (const float*)d_in[2];
  float* out = (float*)d_out;
  char* ws = (char*)d_ws;
  size_t off = 0;
  float* keysT = (float*)(ws + off); off += (size_t)NB * DD * LK * 4;                 // 64 MB
  unsigned short* kbf = (unsigned short*)(ws + off); off += (size_t)NB * LK * DD * 2; // 32 MB
  unsigned short* vt = (unsigned short*)(ws + off); off += (size_t)NB * LK * DD * 2;  // 32 MB
  float* kred = (float*)(ws + off); off += (size_t)NB * DD * 4;
  float* sqkv = (float*)(ws + off); off += (size_t)NB * LQ * 4;
  int* qidx = (int*)(ws + off); off += (size_t)NB * LPAD * 4;
  float* part = (float*)(ws + off); off += (size_t)NB * 128 * DD * 4;                 // 2 MB
  float* meanv = (float*)(ws + off); off += (size_t)NB * DD * 4;
  unsigned char* selflag = (unsigned char*)(ws + off); off += (size_t)NB * LQ;
  // qs aliases keysT's region: keysT dead after k_kreduce, qs written by k_gather after it
  unsigned short* qs = (unsigned short*)keysT;  // 23.1 MB < 64 MB

  hipFuncSetAttribute((const void*)k_attn, hipFuncAttributeMaxDynamicSharedMemorySize, 147456);

  k_transpose<<<dim3(LK / 32, DD / 32, NB), dim3(32, 8), 0, stream>>>(keys, keysT, kbf);
  k_vt<<<dim3(LK / 32, DD / 64, NB), 256, 0, stream>>>(values, vt, part);
  k_kreduce<<<NB * DD, 256, 0, stream>>>(keysT, kred);
  k_sqk<<<NB * LQ / 4, 256, 0, stream>>>(queries, kred, sqkv);
  k_select<<<NB, 512, 0, stream>>>(sqkv, qidx, selflag);
  k_gather<<<dim3(LPAD, NB), 128, 0, stream>>>(queries, qidx, qs);
  k_meanv_fin<<<dim3(DD / 256, NB), 256, 0, stream>>>(part, meanv);
  k_fill<<<NB * LQ / 2, 256, 0, stream>>>((float4*)out, (const float4*)meanv, selflag);
  k_attn<<<dim3((LPAD / 64) * NB), 256, 147456, stream>>>(qs, kbf, vt, qidx, out);
}

// Round 10
// 591.205 us; speedup vs baseline: 1.6345x; 1.4269x over previous
//
#include <hip/hip_runtime.h>
#include <math.h>

#define NB 8
#define LK 4096
#define LQ 4096
#define DD 512
#define LSEL 2744
#define LPAD 2816   // 22 * 128

typedef __attribute__((ext_vector_type(8))) short bf16x8;
typedef __attribute__((ext_vector_type(4))) float f32x4;
typedef __attribute__((ext_vector_type(16))) float f32x16;

#define AS1 __attribute__((address_space(1)))
#define AS3 __attribute__((address_space(3)))

__device__ __forceinline__ unsigned short f2bf(float x) {
  unsigned u = __float_as_uint(x);
  unsigned r = (u + 0x7fffu + ((u >> 16) & 1u)) >> 16;
  return (unsigned short)r;
}

__device__ __forceinline__ unsigned fkey(float x) {
  unsigned b = __float_as_uint(x);
  return (b & 0x80000000u) ? ~b : (b | 0x80000000u);
}

__device__ __forceinline__ unsigned cvt_pk_bf16(float lo, float hi) {
  unsigned r;
  asm("v_cvt_pk_bf16_f32 %0, %1, %2" : "=v"(r) : "v"(lo), "v"(hi));
  return r;
}

// keys f32 [B][LK][D] -> keysT f32 [B][D][LK]  (+ fused bf16 cast of keys)
__global__ void k_transpose(const float* __restrict__ keys, float* __restrict__ keysT,
                            unsigned short* __restrict__ kbf) {
  __shared__ float tile[32][33];
  int b = blockIdx.z;
  int k0 = blockIdx.x * 32, d0 = blockIdx.y * 32;
  int tx = threadIdx.x, ty = threadIdx.y;
  const float* src = keys + ((size_t)b * LK + k0) * DD + d0;
#pragma unroll
  for (int i = 0; i < 4; i++) {
    float v = src[(size_t)(ty + 8 * i) * DD + tx];
    tile[ty + 8 * i][tx] = v;
    kbf[((size_t)b * LK + k0 + ty + 8 * i) * DD + d0 + tx] = f2bf(v);
  }
  __syncthreads();
  float* dst = keysT + ((size_t)b * DD + d0) * LK + k0;
#pragma unroll
  for (int i = 0; i < 4; i++) dst[(size_t)(ty + 8 * i) * LK + tx] = tile[tx][ty + 8 * i];
}

// values f32 [B][LK][D] -> chunk-tiled bf16 VT [B][LK/8][D][8keys]  (+ fused mean partials)
__global__ void k_vt(const float* __restrict__ values, unsigned short* __restrict__ vt,
                     float* __restrict__ part) {
  __shared__ float tile[32][65];
  __shared__ float psum[4][64];
  int b = blockIdx.z, k0 = blockIdx.x * 32, d0 = blockIdx.y * 64;
  int tid = threadIdx.x;
  const float* src = values + ((size_t)b * LK + k0) * DD + d0;
#pragma unroll
  for (int j = 0; j < 8; j++) {
    int li = tid + 256 * j;
    tile[li >> 6][li & 63] = src[(size_t)(li >> 6) * DD + (li & 63)];
  }
  __syncthreads();
  int c = tid >> 6, d = tid & 63;
  union { unsigned short us[8]; uint4 v; } pk;
  float fs = 0.f;
#pragma unroll
  for (int j = 0; j < 8; j++) {
    float v = tile[c * 8 + j][d];
    pk.us[j] = f2bf(v);
    fs += v;
  }
  size_t ci = ((size_t)b * (LK / 8) + (size_t)(k0 >> 3) + c) * DD + d0 + d;
  ((uint4*)vt)[ci] = pk.v;
  psum[c][d] = fs;
  __syncthreads();
  if (tid < 64) {
    float s = psum[0][tid] + psum[1][tid] + psum[2][tid] + psum[3][tid];
    part[((size_t)b * 128 + (k0 >> 5)) * DD + d0 + tid] = s;
  }
}

// per-(b,d): mean of top-LSEL of keysT row; exact radix select, 8-bit digits.
// Pass 1 full scan; then candidates compacted to an LDS list (order-independent
// counting -> deterministic) so passes 2-4 scan only ~16-150 entries.
__global__ __launch_bounds__(256) void k_kreduce(const float* __restrict__ keysT, float* __restrict__ kred) {
  __shared__ unsigned keys[4096];
  __shared__ unsigned cand[4096];
  __shared__ unsigned hist[256];
  __shared__ unsigned sup[16];
  __shared__ unsigned sh_pr[2];
  __shared__ unsigned ccnt;
  __shared__ double redd[256];
  __shared__ unsigned redu[256];
  int row = blockIdx.x;
  int tid = threadIdx.x;
  const float* src = keysT + (size_t)row * LK;
  for (int i = tid; i < LK; i += 256) keys[i] = fkey(src[i]);
  // ---- pass 1: top 8 bits over all 4096 ----
  hist[tid] = 0;
  if (tid == 0) ccnt = 0;
  __syncthreads();
  for (int i = tid; i < LK; i += 256) atomicAdd(&hist[keys[i] >> 24], 1);
  __syncthreads();
  if (tid < 16) {
    unsigned s = 0;
#pragma unroll
    for (int j = 0; j < 16; j++) s += hist[tid * 16 + j];
    sup[tid] = s;
  }
  __syncthreads();
  if (tid == 0) {
    int r = LSEL;
    int sb = 15;
    for (;;) {
      int c = (int)sup[sb];
      if (c >= r) break;
      r -= c;
      if (sb == 0) break;
      sb--;
    }
    int bin = sb * 16 + 15;
    for (;;) {
      int c = (int)hist[bin];
      if (c >= r) break;
      r -= c;
      if (bin == sb * 16) break;
      bin--;
    }
    sh_pr[0] = (unsigned)bin;
    sh_pr[1] = (unsigned)r;
  }
  __syncthreads();
  unsigned prefix = sh_pr[0];
  int rank = (int)sh_pr[1];
  // ---- compact candidates (top byte == prefix) ----
  for (int i = tid; i < LK; i += 256) {
    unsigned u = keys[i];
    if ((u >> 24) == prefix) {
      unsigned p = atomicAdd(&ccnt, 1);
      cand[p] = u;
    }
  }
  __syncthreads();
  int nc = (int)ccnt;
  // ---- passes 2-4 over the candidate list ----
  for (int shift = 16; shift >= 0; shift -= 8) {
    hist[tid] = 0;
    __syncthreads();
    for (int i = tid; i < nc; i += 256) {
      unsigned u = cand[i];
      if ((u >> (shift + 8)) == prefix) atomicAdd(&hist[(u >> shift) & 255], 1);
    }
    __syncthreads();
    if (tid < 16) {
      unsigned s = 0;
#pragma unroll
      for (int j = 0; j < 16; j++) s += hist[tid * 16 + j];
      sup[tid] = s;
    }
    __syncthreads();
    if (tid == 0) {
      int r = rank;
      int sb = 15;
      for (;;) {
        int c = (int)sup[sb];
        if (c >= r) break;
        r -= c;
        if (sb == 0) break;
        sb--;
      }
      int bin = sb * 16 + 15;
      for (;;) {
        int c = (int)hist[bin];
        if (c >= r) break;
        r -= c;
        if (bin == sb * 16) break;
        bin--;
      }
      sh_pr[0] = (prefix << 8) | (unsigned)bin;
      sh_pr[1] = (unsigned)r;
    }
    __syncthreads();
    prefix = sh_pr[0];
    rank = (int)sh_pr[1];
  }
  // ---- final: sum of strictly-greater + threshold fill ----
  double fsum = 0.0;
  unsigned fcnt = 0;
  for (int i = tid; i < LK; i += 256) {
    unsigned u = keys[i];
    if (u > prefix) {
      unsigned bits = (u & 0x80000000u) ? (u ^ 0x80000000u) : ~u;
      fsum += (double)__uint_as_float(bits);
      fcnt++;
    }
  }
  redd[tid] = fsum; redu[tid] = fcnt;
  __syncthreads();
  for (int s = 128; s > 0; s >>= 1) {
    if (tid < s) { redd[tid] += redd[tid + s]; redu[tid] += redu[tid + s]; }
    __syncthreads();
  }
  if (tid == 0) {
    unsigned u = prefix;
    unsigned bits = (u & 0x80000000u) ? (u ^ 0x80000000u) : ~u;
    float tval = __uint_as_float(bits);
    kred[row] = (float)((redd[0] + (double)(LSEL - (int)redu[0]) * (double)tval) / (double)LSEL);
  }
}

// sqk[b][q] = dot(K_reduce[b], queries[b][q]) with f64 accumulation
__global__ __launch_bounds__(256) void k_sqk(const float* __restrict__ queries, const float* __restrict__ kred,
                                             float* __restrict__ sqk) {
  int gw = blockIdx.x * 4 + (threadIdx.x >> 6);
  int lane = threadIdx.x & 63;
  int b = gw >> 12;
  const float* qp = queries + (size_t)gw * DD;
  const float* kp = kred + (size_t)b * DD;
  float4 a0 = ((const float4*)qp)[lane * 2];
  float4 a1 = ((const float4*)qp)[lane * 2 + 1];
  float4 c0 = ((const float4*)kp)[lane * 2];
  float4 c1 = ((const float4*)kp)[lane * 2 + 1];
  double s = (double)a0.x * c0.x + (double)a0.y * c0.y + (double)a0.z * c0.z + (double)a0.w * c0.w +
             (double)a1.x * c1.x + (double)a1.y * c1.y + (double)a1.z * c1.z + (double)a1.w * c1.w;
#pragma unroll
  for (int m = 1; m < 64; m <<= 1) s += __shfl_xor(s, m);
  if (lane == 0) sqk[gw] = (float)s;
}

// per-batch: exact top-LSEL selection (ties by lowest index) + per-row selection flags
__global__ __launch_bounds__(512) void k_select(const float* __restrict__ sqk, int* __restrict__ qidx,
                                                unsigned char* __restrict__ selflag) {
  __shared__ float vals[4096];
  __shared__ unsigned hist[16];
  __shared__ unsigned wsum[8];
  int b = blockIdx.x, tid = threadIdx.x;
  const float* src = sqk + (size_t)b * LQ;
  for (int i = tid; i < LQ; i += 512) vals[i] = src[i];
  __syncthreads();
  unsigned prefix = 0;
  int rank = LSEL;
  for (int shift = 28; shift >= 0; shift -= 4) {
    if (tid < 16) hist[tid] = 0;
    __syncthreads();
    unsigned cnt[16];
#pragma unroll
    for (int j = 0; j < 16; j++) cnt[j] = 0;
    for (int i = tid; i < LQ; i += 512) {
      unsigned u = fkey(vals[i]);
      if (((u >> shift) >> 4) == prefix) cnt[(u >> shift) & 15]++;
    }
#pragma unroll
    for (int j = 0; j < 16; j++) if (cnt[j]) atomicAdd(&hist[j], cnt[j]);
    __syncthreads();
    int r = rank;
    unsigned bin = 15;
    for (;;) {
      int c = (int)hist[bin];
      if (c >= r) break;
      r -= c;
      if (bin == 0) break;
      bin--;
    }
    prefix = (prefix << 4) | bin;
    rank = r;
    __syncthreads();
  }
  unsigned gt = 0, eq = 0;
#pragma unroll
  for (int j = 0; j < 8; j++) {
    int i = tid * 8 + j;
    unsigned u = fkey(vals[i]);
    gt += (u > prefix) ? 1u : 0u;
    eq += (u == prefix) ? 1u : 0u;
  }
  unsigned packed = (gt << 16) | eq;
  unsigned x = packed;
  int lane = tid & 63, wv = tid >> 6;
#pragma unroll
  for (int off2 = 1; off2 < 64; off2 <<= 1) {
    unsigned t = __shfl_up(x, off2);
    if (lane >= off2) x += t;
  }
  if (lane == 63) wsum[wv] = x;
  __syncthreads();
  unsigned wpre = 0, total = 0;
#pragma unroll
  for (int i = 0; i < 8; i++) {
    unsigned v = wsum[i];
    if (i < wv) wpre += v;
    total += v;
  }
  unsigned exclv = x + wpre - packed;
  unsigned total_gt = total >> 16;
  unsigned need_eq = (unsigned)LSEL - total_gt;
  unsigned gpos = exclv >> 16;
  unsigned epos = exclv & 0xffffu;
  for (int j = 0; j < 8; j++) {
    int i = tid * 8 + j;
    unsigned u = fkey(vals[i]);
    unsigned char fl = 0;
    if (u > prefix) {
      qidx[(size_t)b * LPAD + gpos] = i;
      gpos++;
      fl = 1;
    } else if (u == prefix) {
      if (epos < need_eq) {
        qidx[(size_t)b * LPAD + total_gt + epos] = i;
        fl = 1;
      }
      epos++;
    }
    selflag[(size_t)b * LQ + i] = fl;
  }
  for (int p = LSEL + tid; p < LPAD; p += 512) qidx[(size_t)b * LPAD + p] = -1;
}

// gather selected queries -> bf16 [B][LPAD][D], PRE-SCALED by 1/sqrt(D)*log2(e); pad rows zero
__global__ void k_gather(const float* __restrict__ queries, const int* __restrict__ qidx,
                         unsigned short* __restrict__ qs) {
  const float QSCL = 0.04419417418f * 1.4426950408889634f;
  int r = blockIdx.x, b = blockIdx.y;
  int tid = threadIdx.x;
  int q = qidx[(size_t)b * LPAD + r];
  ushort4* dst = (ushort4*)(qs + ((size_t)b * LPAD + r) * DD);
  if (q < 0) {
    ushort4 z; z.x = 0; z.y = 0; z.z = 0; z.w = 0;
    dst[tid] = z;
  } else {
    const float4* srcv = (const float4*)(queries + ((size_t)b * LQ + q) * DD);
    float4 v = srcv[tid];
    ushort4 o;
    o.x = f2bf(v.x * QSCL); o.y = f2bf(v.y * QSCL);
    o.z = f2bf(v.z * QSCL); o.w = f2bf(v.w * QSCL);
    dst[tid] = o;
  }
}

__global__ void k_meanv_fin(const float* __restrict__ part, float* __restrict__ meanv) {
  int d = blockIdx.x * 256 + threadIdx.x;
  int b = blockIdx.y;
  float s = 0.f;
  for (int i = 0; i < 128; i++) s += part[((size_t)b * 128 + i) * DD + d];
  meanv[(size_t)b * DD + d] = s * (1.0f / 4096.0f);
}

// fill ONLY unselected rows with mean-of-values
__global__ void k_fill(float4* __restrict__ out4, const float4* __restrict__ mv4,
                       const unsigned char* __restrict__ flag) {
  int row = blockIdx.x * 2 + (threadIdx.x >> 7);
  int t = threadIdx.x & 127;
  if (flag[row]) return;
  int b = row >> 12;
  out4[(size_t)row * 128 + t] = mv4[b * 128 + t];
}

// flash attention (R7 exact): 8 waves = 4 q-groups x 2 d-waves (2 waves/SIMD on every SIMD),
// Q-tile 128, 32x32x16 swapped-operand MFMA, dbuf K+V via uniform global_load_lds,
// batch->XCD swizzle, Sx partial-S exchange, in-lane softmax, in-register P, setprio.
__global__ __launch_bounds__(512, 2) void k_attn(const unsigned short* __restrict__ qs,
                                                 const unsigned short* __restrict__ kbf,
                                                 const unsigned short* __restrict__ vt,
                                                 const int* __restrict__ qidx,
                                                 float* __restrict__ out) {
  extern __shared__ char smem[];  // [2][K 32KB chunk-major | V 32KB chunk-tiled] | Sx[8][4KB]
  int bi = blockIdx.x;
  int b = bi & 7;              // batch == XCD (round-robin dispatch)
  int q0 = (bi >> 3) * 128;    // 22 q-chunks per batch
  int tid = threadIdx.x;
  int w = tid >> 6, lane = tid & 63;
  int l31 = lane & 31, h = lane >> 5;
  int qg = w >> 1, dg = w & 1;

  // Q as B-frags over this wave's d-slice: lane holds Q[q=l31][dg*256 + t*16 + h*8 ..+7]
  const unsigned short* qrow = qs + ((size_t)b * LPAD + q0 + qg * 32 + l31) * DD + dg * 256;
  bf16x8 qb[16];
#pragma unroll
  for (int t = 0; t < 16; t++) qb[t] = *(const bf16x8*)(qrow + t * 16 + h * 8);

  f32x16 O[8];
#pragma unroll
  for (int n = 0; n < 8; n++)
#pragma unroll
    for (int j = 0; j < 16; j++) O[n][j] = 0.f;
  float m_run = -1e30f, l_run = 0.f;  // per-lane (q = l31, k-half = h)

  const char* gK = (const char*)(kbf + (size_t)b * LK * DD);
  const char* gV = (const char*)vt;

  // K LDS: chunk-major [64 c][32 rows][16B]; V LDS: linear copy of VT tile [4 c][512 d][8k]
  // 8 waves: wave w stages K chunks {w, w+8, w+16, w+24} and V slabs {w, w+8, w+16, w+24}.
#define STAGE(KT, BUF)                                                                          \
  do {                                                                                          \
    char* Kd = smem + (size_t)(BUF)*65536;                                                      \
    char* Vd = Kd + 32768;                                                                      \
    const char* ksrc = gK + (size_t)(KT)*32768 + (size_t)l31 * 1024 + h * 16;                   \
    const char* vsrc = gV + ((size_t)b * 512 + (size_t)(KT)*4) * 8192 + lane * 16;              \
    _Pragma("unroll") for (int j = 0; j < 4; j++) {                                             \
      int u = w + 8 * j;                                                                        \
      __builtin_amdgcn_global_load_lds((const AS1 unsigned int*)(uintptr_t)(ksrc + u * 32),     \
                                       (AS3 unsigned int*)(uintptr_t)(Kd + u * 1024 +           \
                                                                      lane * 16),               \
                                       16, 0, 0);                                               \
    }                                                                                           \
    _Pragma("unroll") for (int j = 0; j < 4; j++) {                                             \
      int s = w + 8 * j;                                                                        \
      __builtin_amdgcn_global_load_lds((const AS1 unsigned int*)(uintptr_t)(vsrc + s * 1024),   \
                                       (AS3 unsigned int*)(uintptr_t)(Vd + s * 1024 +           \
                                                                      lane * 16),               \
                                       16, 0, 0);                                               \
    }                                                                                           \
  } while (0)

  STAGE(0, 0);
  __syncthreads();
  int cur = 0;

  char* mySx = smem + 131072 + (size_t)w * 4096;
  const char* pSx = smem + 131072 + (size_t)(w ^ 1) * 4096;

  for (int kt = 0; kt < LK / 32; kt++) {
    if (kt + 1 < LK / 32) STAGE(kt + 1, cur ^ 1);

    const char* Kl = smem + (size_t)cur * 65536;
    const char* Vl = Kl + 32768;

    // QK^T partial (this wave's 256-d slice): S^T[32k x 32q], lane: q=l31, k=(r&3)+8*(r>>2)+4h
    f32x16 acc;
#pragma unroll
    for (int j = 0; j < 16; j++) acc[j] = 0.f;
    const char* Kp = Kl + (size_t)(dg * 32 + h) * 512 + l31 * 16;
    __builtin_amdgcn_s_setprio(1);
#pragma unroll
    for (int t = 0; t < 16; t++) {
      bf16x8 kf = *(const bf16x8*)(Kp + t * 1024);
      acc = __builtin_amdgcn_mfma_f32_32x32x16_bf16(kf, qb[t], acc, 0, 0, 0);
    }
    __builtin_amdgcn_s_setprio(0);

    // exchange partial S with d-partner wave (linear b128, conflict-free)
#pragma unroll
    for (int j = 0; j < 4; j++) {
      f32x4 v4 = {acc[4 * j], acc[4 * j + 1], acc[4 * j + 2], acc[4 * j + 3]};
      *(f32x4*)(mySx + j * 1024 + lane * 16) = v4;
    }
    asm volatile("s_waitcnt lgkmcnt(0)\ns_barrier" ::: "memory");
#pragma unroll
    for (int j = 0; j < 4; j++) {
      f32x4 v4 = *(const f32x4*)(pSx + j * 1024 + lane * 16);
      acc[4 * j] += v4[0];
      acc[4 * j + 1] += v4[1];
      acc[4 * j + 2] += v4[2];
      acc[4 * j + 3] += v4[3];
    }

    // in-lane softmax (log2 domain; Q pre-scaled by SCALE*log2e)
    float mx = acc[0];
#pragma unroll
    for (int r = 1; r < 16; r++) mx = fmaxf(mx, acc[r]);
    mx = fmaxf(mx, __shfl_xor(mx, 32));
    if (!__all(mx - m_run <= 11.5f)) {
      float mn = fmaxf(m_run, mx);
      float f = exp2f(m_run - mn);
      m_run = mn;
      l_run *= f;
#pragma unroll
      for (int r = 0; r < 16; r++) {
        float fr = __shfl(f, (r & 3) + 8 * (r >> 2) + 4 * h);
#pragma unroll
        for (int n = 0; n < 8; n++) O[n][r] *= fr;
      }
    }
    float ps = 0.f;
#pragma unroll
    for (int r = 0; r < 16; r++) {
      acc[r] = exp2f(acc[r] - m_run);
      ps += acc[r];
    }
    l_run += ps;

    // pack P to bf16 pairs; exchange halves; assemble PV A-frags (layout verified R4)
    unsigned pw[8], px[8];
#pragma unroll
    for (int i = 0; i < 8; i++) pw[i] = cvt_pk_bf16(acc[2 * i], acc[2 * i + 1]);
#pragma unroll
    for (int i = 0; i < 8; i++) px[i] = __shfl_xor(pw[i], 32);
    union { unsigned u[4]; bf16x8 v; } A0, A1;
    A0.u[0] = h ? px[2] : pw[0];
    A0.u[1] = h ? px[3] : pw[1];
    A0.u[2] = h ? pw[2] : px[0];
    A0.u[3] = h ? pw[3] : px[1];
    A1.u[0] = h ? px[6] : pw[4];
    A1.u[1] = h ? px[7] : pw[5];
    A1.u[2] = h ? pw[6] : px[4];
    A1.u[3] = h ? pw[7] : px[5];

    // PV on this wave's 256-d slice: O[32q x 256d] += P[32q x 32k] * V[32k x 256d]
    const char* Vp = Vl + (size_t)h * 8192 + dg * 4096 + l31 * 16;
    __builtin_amdgcn_s_setprio(1);
#pragma unroll
    for (int n = 0; n < 8; n++) {
      bf16x8 b0 = *(const bf16x8*)(Vp + n * 512);
      O[n] = __builtin_amdgcn_mfma_f32_32x32x16_bf16(A0.v, b0, O[n], 0, 0, 0);
      bf16x8 b1 = *(const bf16x8*)(Vp + 16384 + n * 512);
      O[n] = __builtin_amdgcn_mfma_f32_32x32x16_bf16(A1.v, b1, O[n], 0, 0, 0);
    }
    __builtin_amdgcn_s_setprio(0);

    __syncthreads();  // staged kt+1 drained (vmcnt 0) + all waves done with cur bufs + Sx
    cur ^= 1;
  }

  // epilogue: combine k-halves of l, scale, scatter
  float lt = l_run + __shfl_xor(l_run, 32);
  float linv = 1.0f / lt;
  const int* qx = qidx + (size_t)b * LPAD + q0 + qg * 32;
#pragma unroll
  for (int r = 0; r < 16; r++) {
    int row = (r & 3) + 8 * (r >> 2) + 4 * h;
    float sc = __shfl(linv, row);
    int qq = qx[row];
    if (qq >= 0) {
      float* orow = out + ((size_t)b * LQ + qq) * DD + dg * 256 + l31;
#pragma unroll
      for (int n = 0; n < 8; n++) orow[n * 32] = O[n][r] * sc;
    }
  }
#undef STAGE
}

extern "C" void kernel_launch(void* const* d_in, const int* in_sizes, int n_in,
                              void* d_out, int out_size, void* d_ws, size_t ws_size,
                              hipStream_t stream) {
  const float* queries = (const float*)d_in[0];
  const float* keys = (const float*)d_in[1];
  const float* values = (const float*)d_in[2];
  float* out = (float*)d_out;
  char* ws = (char*)d_ws;
  size_t off = 0;
  float* keysT = (float*)(ws + off); off += (size_t)NB * DD * LK * 4;                 // 64 MB
  unsigned short* kbf = (unsigned short*)(ws + off); off += (size_t)NB * LK * DD * 2; // 32 MB
  unsigned short* vt = (unsigned short*)(ws + off); off += (size_t)NB * LK * DD * 2;  // 32 MB
  float* kred = (float*)(ws + off); off += (size_t)NB * DD * 4;
  float* sqkv = (float*)(ws + off); off += (size_t)NB * LQ * 4;
  int* qidx = (int*)(ws + off); off += (size_t)NB * LPAD * 4;
  float* part = (float*)(ws + off); off += (size_t)NB * 128 * DD * 4;                 // 2 MB
  float* meanv = (float*)(ws + off); off += (size_t)NB * DD * 4;
  unsigned char* selflag = (unsigned char*)(ws + off); off += (size_t)NB * LQ;
  // qs aliases keysT's region: keysT dead after k_kreduce, qs written by k_gather after it
  unsigned short* qs = (unsigned short*)keysT;  // 23.1 MB < 64 MB

  hipFuncSetAttribute((const void*)k_attn, hipFuncAttributeMaxDynamicSharedMemorySize, 163840);

  k_transpose<<<dim3(LK / 32, DD / 32, NB), dim3(32, 8), 0, stream>>>(keys, keysT, kbf);
  k_vt<<<dim3(LK / 32, DD / 64, NB), 256, 0, stream>>>(values, vt, part);
  k_kreduce<<<NB * DD, 256, 0, stream>>>(keysT, kred);
  k_sqk<<<NB * LQ / 4, 256, 0, stream>>>(queries, kred, sqkv);
  k_select<<<NB, 512, 0, stream>>>(sqkv, qidx, selflag);
  k_gather<<<dim3(LPAD, NB), 128, 0, stream>>>(queries, qidx, qs);
  k_meanv_fin<<<dim3(DD / 256, NB), 256, 0, stream>>>(part, meanv);
  k_fill<<<NB * LQ / 2, 256, 0, stream>>>((float4*)out, (const float4*)meanv, selflag);
  k_attn<<<dim3((LPAD / 128) * NB), 512, 163840, stream>>>(qs, kbf, vt, qidx, out);
}